// Round 15
// baseline (370.029 us; speedup 1.0000x reference)
//
#include <hip/hip_runtime.h>
#include <hip/hip_fp16.h>

#define BSZ 1024   // B
#define VSZ 4096   // V
#define NBLK 32    // sinkhorn blocks (32 j-rows each, 512 threads)
#define JPB 32     // j's per sinkhorn block
#define KPAD 1040  // LDS row stride for K (1024 + 16 floats)

// ---------------- softmax(y/2) row-wise, writes f16 probs ---------------------
__global__ __launch_bounds__(256) void softmax_kernel(const float* __restrict__ ys,
                                                      const float* __restrict__ yt,
                                                      __half* __restrict__ ps,
                                                      __half* __restrict__ pt) {
    int row = blockIdx.x;
    const float* src;
    __half* dst;
    if (row < BSZ) { src = ys + (size_t)row * VSZ;         dst = ps + (size_t)row * VSZ; }
    else           { src = yt + (size_t)(row - BSZ) * VSZ; dst = pt + (size_t)(row - BSZ) * VSZ; }
    int t = threadIdx.x;
    float4 v[4];
    float m = -1e30f;
#pragma unroll
    for (int k = 0; k < 4; ++k) {
        v[k] = ((const float4*)src)[t + 256 * k];
        m = fmaxf(m, fmaxf(fmaxf(v[k].x, v[k].y), fmaxf(v[k].z, v[k].w)));
    }
#pragma unroll
    for (int d = 32; d >= 1; d >>= 1) m = fmaxf(m, __shfl_down(m, d));
    __shared__ float sred[4];
    __shared__ float sred2[4];
    int lane = t & 63, wid = t >> 6;
    if (lane == 0) sred[wid] = m;
    __syncthreads();
    m = fmaxf(fmaxf(sred[0], sred[1]), fmaxf(sred[2], sred[3]));
    const float C = 0.7213475204444817f;  // 0.5 * log2(e)  (T = 2)
    float s = 0.f;
#pragma unroll
    for (int k = 0; k < 4; ++k) {
        v[k].x = exp2f((v[k].x - m) * C);
        v[k].y = exp2f((v[k].y - m) * C);
        v[k].z = exp2f((v[k].z - m) * C);
        v[k].w = exp2f((v[k].w - m) * C);
        s += (v[k].x + v[k].y) + (v[k].z + v[k].w);
    }
#pragma unroll
    for (int d = 32; d >= 1; d >>= 1) s += __shfl_down(s, d);
    if (lane == 0) sred2[wid] = s;
    __syncthreads();
    s = (sred2[0] + sred2[1]) + (sred2[2] + sred2[3]);
    float inv = 1.0f / s;
#pragma unroll
    for (int k = 0; k < 4; ++k) {
        union { __half h[4]; uint2 u; } o;
        o.h[0] = __float2half(v[k].x * inv);
        o.h[1] = __float2half(v[k].y * inv);
        o.h[2] = __float2half(v[k].z * inv);
        o.h[3] = __float2half(v[k].w * inv);
        ((uint2*)dst)[t + 256 * k] = o.u;
    }
}

// ---------------- S-partial: ST[j][i] = sum_v min(ps[i,v], pt[j,v])  ----------
// R14 unlock: asm MINACC dropped VGPR 152->60 -> register headroom for the
// 128x64 tile that spilled in R6/R11/R12. 256 thr, 8i x 4j/thread: 12
// ds_read_b128 per 256 MACs (0.5 B/MAC, LDS pipe 82->61us). ~110 VGPR est.
// Asm body: v_pk_min x4 + v_pk_add x3 + v_dot2_f32_f16 x1 = 8 insts/8 elems.
// NO VGPR cap ever (R1/R7 law). Watch WRITE_SIZE==16384KB (no spill).
#define TIP 128  // i rows per block
#define TJQ 64   // j rows per block
#define LSTRH 72 // f16 row stride (144 B): 2-way bank aliasing -> free (m136)

__global__ __launch_bounds__(256) void cdist_kernel(const __half* __restrict__ psh,
                                                    const __half* __restrict__ pth,
                                                    float* __restrict__ spart) {
    __shared__ __half sP[2][TIP * LSTRH];  // 36,864 B
    __shared__ __half sQ[2][TJQ * LSTRH];  // 18,432 B  (55.3 KB -> 2 blocks/CU)
    const int bi = blockIdx.x;
    const int bj = blockIdx.y;
    const int bv = blockIdx.z;
    const int t = threadIdx.x;
    const int cl = t & 15;   // i-lane: 8 i's (cl + 16u)
    const int rl = t >> 4;   // j-lane: 4 j's (rl + 16w)
    const __half* psb = psh + ((size_t)bi * TIP) * VSZ + bv * 1024;
    const __half* ptb = pth + ((size_t)bj * TJQ) * VSZ + bv * 1024;
    // P staging: 2 threads/row, 64 contiguous B each (R5-verified, conflict-free)
    const int prow = t >> 1;
    const int pc = (t & 1) * 32;
    const __half* gp = psb + (size_t)prow * VSZ + pc;
    __half* lp0 = &sP[0][prow * LSTRH + pc];
    __half* lp1 = &sP[1][prow * LSTRH + pc];
    // Q staging: 4 threads/row, 32 contiguous B each (uniform 2-way banks: free)
    const int qrow = t >> 2;
    const int qc = (t & 3) * 16;
    const __half* gq = ptb + (size_t)qrow * VSZ + qc;
    __half* lq0 = &sQ[0][qrow * LSTRH + qc];
    __half* lq1 = &sQ[1][qrow * LSTRH + qc];

    const float pk_ones = __uint_as_float(0x3C003C00u);  // packed {1.0h, 1.0h}

    float acc[8][4] = {};

    {   // prologue: stage tile 0 into buf 0
#pragma unroll
        for (int k = 0; k < 4; ++k) *(float4*)(lp0 + 8 * k) = *(const float4*)(gp + 8 * k);
#pragma unroll
        for (int k = 0; k < 2; ++k) *(float4*)(lq0 + 8 * k) = *(const float4*)(gq + 8 * k);
    }
    __syncthreads();

    for (int kt = 0; kt < 16; ++kt) {
        const int cur = kt & 1;
        float4 rp0, rp1, rp2, rp3, rq0, rq1;
        if (kt < 15) {
            const __half* p = gp + (kt + 1) * 64;
            const __half* q = gq + (kt + 1) * 64;
            rp0 = *(const float4*)(p + 0);
            rp1 = *(const float4*)(p + 8);
            rp2 = *(const float4*)(p + 16);
            rp3 = *(const float4*)(p + 24);
            rq0 = *(const float4*)(q + 0);
            rq1 = *(const float4*)(q + 8);
        }
        const __half* pbase = sP[cur] + cl * LSTRH;
        const __half* qbase = sQ[cur] + rl * LSTRH;
#pragma unroll
        for (int vv = 0; vv < 8; ++vv) {
            float4 q0, q1, q2, q3;
            q0 = *(const float4*)(qbase + 0 * 16 * LSTRH + vv * 8);
            q1 = *(const float4*)(qbase + 1 * 16 * LSTRH + vv * 8);
            q2 = *(const float4*)(qbase + 2 * 16 * LSTRH + vv * 8);
            q3 = *(const float4*)(qbase + 3 * 16 * LSTRH + vv * 8);
#define MINACC(A, P, Q)                                                        \
    { float m0_, m1_, m2_, m3_;                                                \
      asm("v_pk_min_f16 %0, %1, %2" : "=v"(m0_) : "v"(P.x), "v"(Q.x));         \
      asm("v_pk_min_f16 %0, %1, %2" : "=v"(m1_) : "v"(P.y), "v"(Q.y));         \
      asm("v_pk_min_f16 %0, %1, %2" : "=v"(m2_) : "v"(P.z), "v"(Q.z));         \
      asm("v_pk_min_f16 %0, %1, %2" : "=v"(m3_) : "v"(P.w), "v"(Q.w));         \
      asm("v_pk_add_f16 %0, %0, %1" : "+v"(m0_) : "v"(m1_));                   \
      asm("v_pk_add_f16 %0, %0, %1" : "+v"(m2_) : "v"(m3_));                   \
      asm("v_pk_add_f16 %0, %0, %1" : "+v"(m0_) : "v"(m2_));                   \
      asm("v_dot2_f32_f16 %0, %1, %2, %0" : "+v"(A) : "v"(m0_), "v"(pk_ones)); }
            // two u-halves of 4 rows each: bounds live p-fragments at 16 regs
#pragma unroll
            for (int h = 0; h < 2; ++h) {
                float4 p0, p1, p2, p3;
                p0 = *(const float4*)(pbase + (h * 4 + 0) * 16 * LSTRH + vv * 8);
                p1 = *(const float4*)(pbase + (h * 4 + 1) * 16 * LSTRH + vv * 8);
                p2 = *(const float4*)(pbase + (h * 4 + 2) * 16 * LSTRH + vv * 8);
                p3 = *(const float4*)(pbase + (h * 4 + 3) * 16 * LSTRH + vv * 8);
                MINACC(acc[h * 4 + 0][0], p0, q0) MINACC(acc[h * 4 + 0][1], p0, q1)
                MINACC(acc[h * 4 + 0][2], p0, q2) MINACC(acc[h * 4 + 0][3], p0, q3)
                MINACC(acc[h * 4 + 1][0], p1, q0) MINACC(acc[h * 4 + 1][1], p1, q1)
                MINACC(acc[h * 4 + 1][2], p1, q2) MINACC(acc[h * 4 + 1][3], p1, q3)
                MINACC(acc[h * 4 + 2][0], p2, q0) MINACC(acc[h * 4 + 2][1], p2, q1)
                MINACC(acc[h * 4 + 2][2], p2, q2) MINACC(acc[h * 4 + 2][3], p2, q3)
                MINACC(acc[h * 4 + 3][0], p3, q0) MINACC(acc[h * 4 + 3][1], p3, q1)
                MINACC(acc[h * 4 + 3][2], p3, q2) MINACC(acc[h * 4 + 3][3], p3, q3)
            }
#undef MINACC
        }
        if (kt < 15) {
            __half* lp = cur ? lp0 : lp1;
            __half* lq = cur ? lq0 : lq1;
            *(float4*)(lp + 0)  = rp0;
            *(float4*)(lp + 8)  = rp1;
            *(float4*)(lp + 16) = rp2;
            *(float4*)(lp + 24) = rp3;
            *(float4*)(lq + 0)  = rq0;
            *(float4*)(lq + 8)  = rq1;
        }
        __syncthreads();
    }

    float* outp = spart + (size_t)bv * (BSZ * BSZ);
#pragma unroll
    for (int w = 0; w < 4; ++w) {
        int jr = bj * TJQ + rl + 16 * w;
#pragma unroll
        for (int u = 0; u < 8; ++u) {
            int ic = bi * TIP + cl + 16 * u;
            outp[(size_t)jr * BSZ + ic] = acc[u][w];
        }
    }
}

// ------- combine v-partials: W = 2 - 2*S, K = exp(-W/eps); init barrier flags -
__global__ __launch_bounds__(256) void combine_kernel(const float* __restrict__ spart,
                                                      float* __restrict__ wt,
                                                      float* __restrict__ kt,
                                                      unsigned* __restrict__ flags) {
    if (blockIdx.x == 0 && threadIdx.x < NBLK) flags[threadIdx.x * 32] = 0u;
    int idx = blockIdx.x * 256 + threadIdx.x;  // over B*B/4 float4s
    const float4* p0 = (const float4*)spart;
    const int Q = (BSZ * BSZ) / 4;
    float4 a = p0[idx], b = p0[idx + Q], c = p0[idx + 2 * Q], d = p0[idx + 3 * Q];
    float4 w;
    w.x = 2.0f - 2.0f * ((a.x + b.x) + (c.x + d.x));
    w.y = 2.0f - 2.0f * ((a.y + b.y) + (c.y + d.y));
    w.z = 2.0f - 2.0f * ((a.z + b.z) + (c.z + d.z));
    w.w = 2.0f - 2.0f * ((a.w + b.w) + (c.w + d.w));
    ((float4*)wt)[idx] = w;
    const float CE = -14.426950408889634f;  // -log2(e)/eps, eps=0.1
    float4 k;
    k.x = exp2f(w.x * CE);
    k.y = exp2f(w.y * CE);
    k.z = exp2f(w.z * CE);
    k.w = exp2f(w.w * CE);
    ((float4*)kt)[idx] = k;
}

// ------- grid barrier v4: all-to-all (no master/go relay hop) -----------------
__device__ inline void grid_barrier(unsigned* flags, unsigned gen) {
    __syncthreads();
    const int t = threadIdx.x;
    if (t == 0)  // RELEASE: flush this block's cpart/outpart stores
        __hip_atomic_store(&flags[blockIdx.x * 32], gen, __ATOMIC_RELEASE, __HIP_MEMORY_SCOPE_AGENT);
    if (t < NBLK) {
        while (__hip_atomic_load(&flags[t * 32], __ATOMIC_RELAXED, __HIP_MEMORY_SCOPE_AGENT) < gen)
            __builtin_amdgcn_s_sleep(1);
    }
    __syncthreads();
    if (t == 0)  // single ACQUIRE: one L1/L2 inv for the whole block
        (void)__hip_atomic_load(&flags[0], __ATOMIC_ACQUIRE, __HIP_MEMORY_SCOPE_AGENT);
    __syncthreads();
}

// ---------------- Sinkhorn: a = 1/(K b); b = 1/(K^T a), 20 iters + final sum --
__global__ __launch_bounds__(512) void sinkhorn_kernel(const float* __restrict__ KT,
                                                       const float* __restrict__ WT,
                                                       float* __restrict__ cpart,
                                                       float* __restrict__ outpart,
                                                       float* __restrict__ out,
                                                       unsigned* __restrict__ flags) {
    __shared__ __align__(16) float k_lds[JPB * KPAD];   // 133,120 B
    __shared__ __align__(16) float a_sh[BSZ];
    __shared__ float b_sh[JPB];
    __shared__ float red[JPB];
    const int z = blockIdx.x;
    const int t = threadIdx.x;
    const int j0 = z * JPB;
#pragma unroll
    for (int m = 0; m < 16; ++m) {
        int idx = t + 512 * m;
        int row = idx >> 8;
        int col = (idx & 255) * 4;
        float4 v = *(const float4*)(KT + (size_t)(j0 + row) * BSZ + col);
        *(float4*)(&k_lds[row * KPAD + col]) = v;
    }
    if (t < JPB) b_sh[t] = 1.0f;
    __syncthreads();
    const int jj = t >> 4;   // 0..31
    const int il = t & 15;
    unsigned gen = 1u;
    for (int it = 0; it < 20; ++it) {
        float* cur = cpart + (size_t)(it & 1) * (NBLK * BSZ) + (size_t)z * BSZ;
        float2 s = {0.f, 0.f};
#pragma unroll
        for (int q = 0; q < JPB; ++q) {
            float2 kv = *(const float2*)(&k_lds[q * KPAD + 2 * t]);
            float bb = b_sh[q];
            s.x += kv.x * bb; s.y += kv.y * bb;
        }
        ((float2*)cur)[t] = s;
        grid_barrier(flags, gen++);
        const float* curAll = cpart + (size_t)(it & 1) * (NBLK * BSZ);
        float2 c = {0.f, 0.f};
#pragma unroll 8
        for (int zz = 0; zz < NBLK; ++zz) {
            float2 v = ((const float2*)curAll)[zz * 512 + t];
            c.x += v.x; c.y += v.y;
        }
        float2 ar;
        ar.x = 1.0f / c.x; ar.y = 1.0f / c.y;
        ((float2*)a_sh)[t] = ar;
        __syncthreads();
        float sb = 0.f;
#pragma unroll
        for (int m2 = 0; m2 < 16; ++m2) {
            float4 kv = *(const float4*)(&k_lds[jj * KPAD + (il + 16 * m2) * 4]);
            float4 av = ((const float4*)a_sh)[il + 16 * m2];
            sb += (kv.x * av.x + kv.y * av.y) + (kv.z * av.z + kv.w * av.w);
        }
#pragma unroll
        for (int d = 8; d >= 1; d >>= 1) sb += __shfl_down(sb, d, 16);
        if (il == 0) b_sh[jj] = 1.0f / sb;
        __syncthreads();
    }
    {
        const float4* wrow = (const float4*)(WT + (size_t)(j0 + jj) * BSZ);
        float sb = 0.f;
#pragma unroll 4
        for (int m2 = 0; m2 < 16; ++m2) {
            float4 kv = *(const float4*)(&k_lds[jj * KPAD + (il + 16 * m2) * 4]);
            float4 wv = wrow[il + 16 * m2];
            float4 av = ((const float4*)a_sh)[il + 16 * m2];
            sb += (av.x * kv.x * wv.x + av.y * kv.y * wv.y) +
                  (av.z * kv.z * wv.z + av.w * kv.w * wv.w);
        }
#pragma unroll
        for (int d = 8; d >= 1; d >>= 1) sb += __shfl_down(sb, d, 16);
        if (il == 0) red[jj] = sb * b_sh[jj];
        __syncthreads();
        if (t == 0) {
            float ss = 0.f;
#pragma unroll
            for (int q = 0; q < JPB; ++q) ss += red[q];
            outpart[z] = ss;
        }
    }
    grid_barrier(flags, gen++);
    if (z == 0 && t == 0) {
        float ss = 0.f;
        for (int q = 0; q < NBLK; ++q) ss += outpart[q];
        out[0] = 0.001f * ss;
    }
}

extern "C" void kernel_launch(void* const* d_in, const int* in_sizes, int n_in,
                              void* d_out, int out_size, void* d_ws, size_t ws_size,
                              hipStream_t stream) {
    const float* ys = (const float*)d_in[0];
    const float* yt = (const float*)d_in[1];
    float* ws = (float*)d_ws;
    __half* psh    = (__half*)ws;                          // 2M floats
    __half* pth    = (__half*)(ws + 2ull * 1024 * 1024);   // 2M floats
    float* spart   = ws + 4ull * 1024 * 1024;              // 4 x 1M
    float* wt      = spart + 4ull * BSZ * BSZ;             // 1M
    float* kt      = wt + (size_t)BSZ * BSZ;               // 1M
    float* cpart   = kt + (size_t)BSZ * BSZ;               // 2*32*1024
    float* outpart = cpart + 2ull * NBLK * BSZ;            // 32 (+pad)
    unsigned* flags = (unsigned*)(outpart + 128);          // NBLK x 32 uints
    float* outp    = (float*)d_out;

    softmax_kernel<<<dim3(2 * BSZ), dim3(256), 0, stream>>>(ys, yt, psh, pth);
    cdist_kernel<<<dim3(8, 16, 4), dim3(256), 0, stream>>>(psh, pth, spart);
    combine_kernel<<<dim3((BSZ * BSZ / 4) / 256), dim3(256), 0, stream>>>(spart, wt, kt, flags);

    void* args[] = {(void*)&kt, (void*)&wt, (void*)&cpart, (void*)&outpart, (void*)&outp,
                    (void*)&flags};
    (void)hipLaunchCooperativeKernel((void*)sinkhorn_kernel, dim3(NBLK), dim3(512), args, 0, stream);
}

// Round 16
// 360.831 us; speedup vs baseline: 1.0255x; 1.0255x over previous
//
#include <hip/hip_runtime.h>
#include <hip/hip_fp16.h>

#define BSZ 1024   // B
#define VSZ 4096   // V
#define NBLK 32    // sinkhorn blocks (32 j-rows each, 512 threads)
#define JPB 32     // j's per sinkhorn block
#define KPAD 1040  // LDS row stride for K (1024 + 16 floats)

// ---------------- softmax(y/2) row-wise, writes f16 probs ---------------------
__global__ __launch_bounds__(256) void softmax_kernel(const float* __restrict__ ys,
                                                      const float* __restrict__ yt,
                                                      __half* __restrict__ ps,
                                                      __half* __restrict__ pt) {
    int row = blockIdx.x;
    const float* src;
    __half* dst;
    if (row < BSZ) { src = ys + (size_t)row * VSZ;         dst = ps + (size_t)row * VSZ; }
    else           { src = yt + (size_t)(row - BSZ) * VSZ; dst = pt + (size_t)(row - BSZ) * VSZ; }
    int t = threadIdx.x;
    float4 v[4];
    float m = -1e30f;
#pragma unroll
    for (int k = 0; k < 4; ++k) {
        v[k] = ((const float4*)src)[t + 256 * k];
        m = fmaxf(m, fmaxf(fmaxf(v[k].x, v[k].y), fmaxf(v[k].z, v[k].w)));
    }
#pragma unroll
    for (int d = 32; d >= 1; d >>= 1) m = fmaxf(m, __shfl_down(m, d));
    __shared__ float sred[4];
    __shared__ float sred2[4];
    int lane = t & 63, wid = t >> 6;
    if (lane == 0) sred[wid] = m;
    __syncthreads();
    m = fmaxf(fmaxf(sred[0], sred[1]), fmaxf(sred[2], sred[3]));
    const float C = 0.7213475204444817f;  // 0.5 * log2(e)  (T = 2)
    float s = 0.f;
#pragma unroll
    for (int k = 0; k < 4; ++k) {
        v[k].x = exp2f((v[k].x - m) * C);
        v[k].y = exp2f((v[k].y - m) * C);
        v[k].z = exp2f((v[k].z - m) * C);
        v[k].w = exp2f((v[k].w - m) * C);
        s += (v[k].x + v[k].y) + (v[k].z + v[k].w);
    }
#pragma unroll
    for (int d = 32; d >= 1; d >>= 1) s += __shfl_down(s, d);
    if (lane == 0) sred2[wid] = s;
    __syncthreads();
    s = (sred2[0] + sred2[1]) + (sred2[2] + sred2[3]);
    float inv = 1.0f / s;
#pragma unroll
    for (int k = 0; k < 4; ++k) {
        union { __half h[4]; uint2 u; } o;
        o.h[0] = __float2half(v[k].x * inv);
        o.h[1] = __float2half(v[k].y * inv);
        o.h[2] = __float2half(v[k].z * inv);
        o.h[3] = __float2half(v[k].w * inv);
        ((uint2*)dst)[t + 256 * k] = o.u;
    }
}

// ---------------- S-partial: ST[j][i] = sum_v min(ps[i,v], pt[j,v])  ----------
// R14 champion tile (64x64, 4x4/thread, asm MINACC, VGPR~60) + SINGLE-buffer
// LDS: 18.4 KB -> 8 blocks/CU = 32 waves/CU (max). 2 syncs/tile, but with 8
// co-resident blocks the stalls overlap across blocks (m114). R15's 128x64
// regressed on occupancy (2 blocks/CU); R6/R11/R12 spilled. Do not cap VGPR.
#define TS 64
#define LSTRH 72  // f16 row stride (144 B): 2-way bank aliasing -> free (m136)

__global__ __launch_bounds__(256) void cdist_kernel(const __half* __restrict__ psh,
                                                    const __half* __restrict__ pth,
                                                    float* __restrict__ spart) {
    __shared__ __half sP[TS * LSTRH];   // 9,216 B
    __shared__ __half sQ[TS * LSTRH];   // 9,216 B  (18.4 KB total)
    const int bi = blockIdx.x;
    const int bj = blockIdx.y;
    const int bv = blockIdx.z;
    const int t = threadIdx.x;
    const int cl = t & 15;   // i-lane
    const int rl = t >> 4;   // j-lane
    const __half* psb = psh + ((size_t)bi * TS) * VSZ + bv * 1024;
    const __half* ptb = pth + ((size_t)bj * TS) * VSZ + bv * 1024;
    const int isP = (t < 128);
    const int lt = t & 127;
    const int srow = lt >> 1;            // 0..63
    const int sc0 = (lt & 1) * 32;       // half-offset: 0 or 32
    const __half* gsrc = (isP ? psb : ptb) + (size_t)srow * VSZ + sc0;
    __half* lbase = (isP ? sP : sQ) + srow * LSTRH + sc0;

    const float pk_ones = __uint_as_float(0x3C003C00u);  // packed {1.0h, 1.0h}

    float a00 = 0.f, a01 = 0.f, a02 = 0.f, a03 = 0.f;
    float a10 = 0.f, a11 = 0.f, a12 = 0.f, a13 = 0.f;
    float a20 = 0.f, a21 = 0.f, a22 = 0.f, a23 = 0.f;
    float a30 = 0.f, a31 = 0.f, a32 = 0.f, a33 = 0.f;

    {   // stage tile 0
        float4 r0 = *(const float4*)(gsrc + 0);
        float4 r1 = *(const float4*)(gsrc + 8);
        float4 r2 = *(const float4*)(gsrc + 16);
        float4 r3 = *(const float4*)(gsrc + 24);
        *(float4*)(lbase + 0)  = r0;
        *(float4*)(lbase + 8)  = r1;
        *(float4*)(lbase + 16) = r2;
        *(float4*)(lbase + 24) = r3;
    }
    __syncthreads();

    for (int kt = 0; kt < 16; ++kt) {
        float4 rn0, rn1, rn2, rn3;
        if (kt < 15) {  // prefetch next tile into registers (hides HBM latency)
            const __half* g = gsrc + (kt + 1) * 64;
            rn0 = *(const float4*)(g + 0);
            rn1 = *(const float4*)(g + 8);
            rn2 = *(const float4*)(g + 16);
            rn3 = *(const float4*)(g + 24);
        }
        const __half* pbase = sP + cl * LSTRH;
        const __half* qbase = sQ + rl * LSTRH;
#pragma unroll
        for (int vv = 0; vv < 8; ++vv) {
            float4 p0, p1, p2, p3, q0, q1, q2, q3;
            q0 = *(const float4*)(qbase + 0 * 16 * LSTRH + vv * 8);
            q1 = *(const float4*)(qbase + 1 * 16 * LSTRH + vv * 8);
            q2 = *(const float4*)(qbase + 2 * 16 * LSTRH + vv * 8);
            q3 = *(const float4*)(qbase + 3 * 16 * LSTRH + vv * 8);
            p0 = *(const float4*)(pbase + 0 * 16 * LSTRH + vv * 8);
            p1 = *(const float4*)(pbase + 1 * 16 * LSTRH + vv * 8);
            p2 = *(const float4*)(pbase + 2 * 16 * LSTRH + vv * 8);
            p3 = *(const float4*)(pbase + 3 * 16 * LSTRH + vv * 8);
#define MINACC(A, P, Q)                                                        \
    { float m0_, m1_, m2_, m3_;                                                \
      asm("v_pk_min_f16 %0, %1, %2" : "=v"(m0_) : "v"(P.x), "v"(Q.x));         \
      asm("v_pk_min_f16 %0, %1, %2" : "=v"(m1_) : "v"(P.y), "v"(Q.y));         \
      asm("v_pk_min_f16 %0, %1, %2" : "=v"(m2_) : "v"(P.z), "v"(Q.z));         \
      asm("v_pk_min_f16 %0, %1, %2" : "=v"(m3_) : "v"(P.w), "v"(Q.w));         \
      asm("v_pk_add_f16 %0, %0, %1" : "+v"(m0_) : "v"(m1_));                   \
      asm("v_pk_add_f16 %0, %0, %1" : "+v"(m2_) : "v"(m3_));                   \
      asm("v_pk_add_f16 %0, %0, %1" : "+v"(m0_) : "v"(m2_));                   \
      asm("v_dot2_f32_f16 %0, %1, %2, %0" : "+v"(A) : "v"(m0_), "v"(pk_ones)); }
            MINACC(a00, p0, q0) MINACC(a01, p1, q0) MINACC(a02, p2, q0) MINACC(a03, p3, q0)
            MINACC(a10, p0, q1) MINACC(a11, p1, q1) MINACC(a12, p2, q1) MINACC(a13, p3, q1)
            MINACC(a20, p0, q2) MINACC(a21, p1, q2) MINACC(a22, p2, q2) MINACC(a23, p3, q2)
            MINACC(a30, p0, q3) MINACC(a31, p1, q3) MINACC(a32, p2, q3) MINACC(a33, p3, q3)
#undef MINACC
        }
        __syncthreads();   // compute done -> safe to overwrite LDS
        if (kt < 15) {
            *(float4*)(lbase + 0)  = rn0;
            *(float4*)(lbase + 8)  = rn1;
            *(float4*)(lbase + 16) = rn2;
            *(float4*)(lbase + 24) = rn3;
            __syncthreads();  // staging done -> safe to read
        }
    }

    float* outp = spart + (size_t)bv * (BSZ * BSZ);
    float accs[4][4] = {{a00, a01, a02, a03},
                        {a10, a11, a12, a13},
                        {a20, a21, a22, a23},
                        {a30, a31, a32, a33}};
#pragma unroll
    for (int w = 0; w < 4; ++w) {
        int jr = bj * TS + rl + 16 * w;
#pragma unroll
        for (int u = 0; u < 4; ++u) {
            int ic = bi * TS + cl + 16 * u;
            outp[(size_t)jr * BSZ + ic] = accs[w][u];
        }
    }
}

// ------- combine v-partials: W = 2 - 2*S, K = exp(-W/eps); init barrier flags -
__global__ __launch_bounds__(256) void combine_kernel(const float* __restrict__ spart,
                                                      float* __restrict__ wt,
                                                      float* __restrict__ kt,
                                                      unsigned* __restrict__ flags) {
    if (blockIdx.x == 0 && threadIdx.x < NBLK) flags[threadIdx.x * 32] = 0u;
    int idx = blockIdx.x * 256 + threadIdx.x;  // over B*B/4 float4s
    const float4* p0 = (const float4*)spart;
    const int Q = (BSZ * BSZ) / 4;
    float4 a = p0[idx], b = p0[idx + Q], c = p0[idx + 2 * Q], d = p0[idx + 3 * Q];
    float4 w;
    w.x = 2.0f - 2.0f * ((a.x + b.x) + (c.x + d.x));
    w.y = 2.0f - 2.0f * ((a.y + b.y) + (c.y + d.y));
    w.z = 2.0f - 2.0f * ((a.z + b.z) + (c.z + d.z));
    w.w = 2.0f - 2.0f * ((a.w + b.w) + (c.w + d.w));
    ((float4*)wt)[idx] = w;
    const float CE = -14.426950408889634f;  // -log2(e)/eps, eps=0.1
    float4 k;
    k.x = exp2f(w.x * CE);
    k.y = exp2f(w.y * CE);
    k.z = exp2f(w.z * CE);
    k.w = exp2f(w.w * CE);
    ((float4*)kt)[idx] = k;
}

// ------- grid barrier v4: all-to-all (no master/go relay hop) -----------------
__device__ inline void grid_barrier(unsigned* flags, unsigned gen) {
    __syncthreads();
    const int t = threadIdx.x;
    if (t == 0)  // RELEASE: flush this block's cpart/outpart stores
        __hip_atomic_store(&flags[blockIdx.x * 32], gen, __ATOMIC_RELEASE, __HIP_MEMORY_SCOPE_AGENT);
    if (t < NBLK) {
        while (__hip_atomic_load(&flags[t * 32], __ATOMIC_RELAXED, __HIP_MEMORY_SCOPE_AGENT) < gen)
            __builtin_amdgcn_s_sleep(1);
    }
    __syncthreads();
    if (t == 0)  // single ACQUIRE: one L1/L2 inv for the whole block
        (void)__hip_atomic_load(&flags[0], __ATOMIC_ACQUIRE, __HIP_MEMORY_SCOPE_AGENT);
    __syncthreads();
}

// ---------------- Sinkhorn: a = 1/(K b); b = 1/(K^T a), 20 iters + final sum --
__global__ __launch_bounds__(512) void sinkhorn_kernel(const float* __restrict__ KT,
                                                       const float* __restrict__ WT,
                                                       float* __restrict__ cpart,
                                                       float* __restrict__ outpart,
                                                       float* __restrict__ out,
                                                       unsigned* __restrict__ flags) {
    __shared__ __align__(16) float k_lds[JPB * KPAD];   // 133,120 B
    __shared__ __align__(16) float a_sh[BSZ];
    __shared__ float b_sh[JPB];
    __shared__ float red[JPB];
    const int z = blockIdx.x;
    const int t = threadIdx.x;
    const int j0 = z * JPB;
#pragma unroll
    for (int m = 0; m < 16; ++m) {
        int idx = t + 512 * m;
        int row = idx >> 8;
        int col = (idx & 255) * 4;
        float4 v = *(const float4*)(KT + (size_t)(j0 + row) * BSZ + col);
        *(float4*)(&k_lds[row * KPAD + col]) = v;
    }
    if (t < JPB) b_sh[t] = 1.0f;
    __syncthreads();
    const int jj = t >> 4;   // 0..31
    const int il = t & 15;
    unsigned gen = 1u;
    for (int it = 0; it < 20; ++it) {
        float* cur = cpart + (size_t)(it & 1) * (NBLK * BSZ) + (size_t)z * BSZ;
        float2 s = {0.f, 0.f};
#pragma unroll
        for (int q = 0; q < JPB; ++q) {
            float2 kv = *(const float2*)(&k_lds[q * KPAD + 2 * t]);
            float bb = b_sh[q];
            s.x += kv.x * bb; s.y += kv.y * bb;
        }
        ((float2*)cur)[t] = s;
        grid_barrier(flags, gen++);
        const float* curAll = cpart + (size_t)(it & 1) * (NBLK * BSZ);
        float2 c = {0.f, 0.f};
#pragma unroll 8
        for (int zz = 0; zz < NBLK; ++zz) {
            float2 v = ((const float2*)curAll)[zz * 512 + t];
            c.x += v.x; c.y += v.y;
        }
        float2 ar;
        ar.x = 1.0f / c.x; ar.y = 1.0f / c.y;
        ((float2*)a_sh)[t] = ar;
        __syncthreads();
        float sb = 0.f;
#pragma unroll
        for (int m2 = 0; m2 < 16; ++m2) {
            float4 kv = *(const float4*)(&k_lds[jj * KPAD + (il + 16 * m2) * 4]);
            float4 av = ((const float4*)a_sh)[il + 16 * m2];
            sb += (kv.x * av.x + kv.y * av.y) + (kv.z * av.z + kv.w * av.w);
        }
#pragma unroll
        for (int d = 8; d >= 1; d >>= 1) sb += __shfl_down(sb, d, 16);
        if (il == 0) b_sh[jj] = 1.0f / sb;
        __syncthreads();
    }
    {
        const float4* wrow = (const float4*)(WT + (size_t)(j0 + jj) * BSZ);
        float sb = 0.f;
#pragma unroll 4
        for (int m2 = 0; m2 < 16; ++m2) {
            float4 kv = *(const float4*)(&k_lds[jj * KPAD + (il + 16 * m2) * 4]);
            float4 wv = wrow[il + 16 * m2];
            float4 av = ((const float4*)a_sh)[il + 16 * m2];
            sb += (av.x * kv.x * wv.x + av.y * kv.y * wv.y) +
                  (av.z * kv.z * wv.z + av.w * kv.w * wv.w);
        }
#pragma unroll
        for (int d = 8; d >= 1; d >>= 1) sb += __shfl_down(sb, d, 16);
        if (il == 0) red[jj] = sb * b_sh[jj];
        __syncthreads();
        if (t == 0) {
            float ss = 0.f;
#pragma unroll
            for (int q = 0; q < JPB; ++q) ss += red[q];
            outpart[z] = ss;
        }
    }
    grid_barrier(flags, gen++);
    if (z == 0 && t == 0) {
        float ss = 0.f;
        for (int q = 0; q < NBLK; ++q) ss += outpart[q];
        out[0] = 0.001f * ss;
    }
}

extern "C" void kernel_launch(void* const* d_in, const int* in_sizes, int n_in,
                              void* d_out, int out_size, void* d_ws, size_t ws_size,
                              hipStream_t stream) {
    const float* ys = (const float*)d_in[0];
    const float* yt = (const float*)d_in[1];
    float* ws = (float*)d_ws;
    __half* psh    = (__half*)ws;                          // 2M floats
    __half* pth    = (__half*)(ws + 2ull * 1024 * 1024);   // 2M floats
    float* spart   = ws + 4ull * 1024 * 1024;              // 4 x 1M
    float* wt      = spart + 4ull * BSZ * BSZ;             // 1M
    float* kt      = wt + (size_t)BSZ * BSZ;               // 1M
    float* cpart   = kt + (size_t)BSZ * BSZ;               // 2*32*1024
    float* outpart = cpart + 2ull * NBLK * BSZ;            // 32 (+pad)
    unsigned* flags = (unsigned*)(outpart + 128);          // NBLK x 32 uints
    float* outp    = (float*)d_out;

    softmax_kernel<<<dim3(2 * BSZ), dim3(256), 0, stream>>>(ys, yt, psh, pth);
    cdist_kernel<<<dim3(16, 16, 4), dim3(256), 0, stream>>>(psh, pth, spart);
    combine_kernel<<<dim3((BSZ * BSZ / 4) / 256), dim3(256), 0, stream>>>(spart, wt, kt, flags);

    void* args[] = {(void*)&kt, (void*)&wt, (void*)&cpart, (void*)&outpart, (void*)&outp,
                    (void*)&flags};
    (void)hipLaunchCooperativeKernel((void*)sinkhorn_kernel, dim3(NBLK), dim3(512), args, 0, stream);
}